// Round 13
// baseline (155.823 us; speedup 1.0000x reference)
//
#include <hip/hip_runtime.h>
#include <hip/hip_bf16.h>

typedef __bf16 bf16x8 __attribute__((ext_vector_type(8)));
typedef float f32x4 __attribute__((ext_vector_type(4)));
typedef unsigned short u16x4 __attribute__((ext_vector_type(4)));
typedef unsigned short u16x8 __attribute__((ext_vector_type(8)));

__device__ __forceinline__ unsigned short f2bf(float f) {
  unsigned int u = __float_as_uint(f);
  u += 0x7FFFu + ((u >> 16) & 1u);   // round-to-nearest-even
  return (unsigned short)(u >> 16);
}

__device__ __forceinline__ float exp2_fast(float x) {
  return __builtin_amdgcn_exp2f(x);   // v_exp_f32
}

// pack two fp32 -> two bf16 (truncating) in one v_perm_b32
__device__ __forceinline__ unsigned pack_bf16(float lo, float hi) {
  return __builtin_amdgcn_perm(__float_as_uint(hi), __float_as_uint(lo), 0x07060302u);
}

// async global->LDS, 16B per lane; LDS dest = wave-uniform base + lane*16
__device__ __forceinline__ void gld_lds16(const void* g, void* l) {
  __builtin_amdgcn_global_load_lds(
      (__attribute__((address_space(1))) void*)g,
      (__attribute__((address_space(3))) void*)l,
      16, 0, 0);
}

// ---------------------------------------------------------------------------
// fp32 -> bf16 conversion pre-pass: X (8.4M elems) + Wq,Wk,Wv,Wo (1M each).
// ---------------------------------------------------------------------------
__global__ __launch_bounds__(256)
void cvt_bf16(const float* __restrict__ x, const float* __restrict__ wq,
              const float* __restrict__ wk, const float* __restrict__ wv,
              const float* __restrict__ wo,
              unsigned short* __restrict__ Xb, unsigned short* __restrict__ Wb)
{
  unsigned c = blockIdx.x * 256 + threadIdx.x;
  const float* src;
  unsigned short* dst;
  unsigned off;
  if (c < 1048576u) {               // X: 1048576 chunks
    src = x; dst = Xb; off = c;
  } else {                          // W's: 131072 chunks each
    unsigned cc = c - 1048576u;
    unsigned which = cc >> 17;
    off = cc & 131071u;
    src = which == 0 ? wq : which == 1 ? wk : which == 2 ? wv : wo;
    dst = Wb + (size_t)which * 1048576u;
  }
  f32x4 a = *reinterpret_cast<const f32x4*>(src + (size_t)off * 8);
  f32x4 b = *reinterpret_cast<const f32x4*>(src + (size_t)off * 8 + 4);
  u16x8 o = {f2bf(a.x), f2bf(a.y), f2bf(a.z), f2bf(a.w),
             f2bf(b.x), f2bf(b.y), f2bf(b.z), f2bf(b.w)};
  *reinterpret_cast<u16x8*>(dst + (size_t)off * 8) = o;
}

// ---------------------------------------------------------------------------
// bf16 GEMM C[m,n] = sum_k A[m,k]*W[n,k] via global_load_lds staging.
// ---------------------------------------------------------------------------
__global__ __launch_bounds__(256, 3)
void qkv_proj_b(const unsigned short* __restrict__ Xb, const unsigned short* __restrict__ Wb,
                unsigned short* __restrict__ Qb, unsigned short* __restrict__ Kb,
                unsigned short* __restrict__ Vb)
{
  __shared__ __align__(16) unsigned short As[128 * 64];
  __shared__ __align__(16) unsigned short Bs[128 * 64];
  char* AsB = (char*)As;
  char* BsB = (char*)Bs;

  const int z = blockIdx.z;
  const unsigned short* __restrict__ W = Wb + (size_t)z * 1048576u;
  unsigned short* __restrict__ Out = (z == 0) ? Qb : (z == 1) ? Kb : Vb;

  const int flat = blockIdx.x + (blockIdx.y << 3);
  const int swz = (flat & 7) * 64 + (flat >> 3);
  const int n0 = (swz & 7) * 128;
  const int m0 = (swz >> 3) * 128;

  const int t = threadIdx.x;
  const int lane = t & 63, wid = t >> 6;
  const int wr = wid >> 1, wc = wid & 1;
  const int l15 = lane & 15, g = lane >> 4;

  f32x4 acc[4][4] = {};

  for (int kt = 0; kt < 1024; kt += 64) {
#pragma unroll
    for (int i = 0; i < 4; ++i) {
      const int rbase = wid * 32 + i * 8;
      const int row = rbase + (lane >> 3);
      const int swzb = ((lane & 7) * 16) ^ ((row & 7) << 4);
      gld_lds16((const char*)Xb + ((size_t)(m0 + row) * 1024 + kt) * 2 + swzb,
                AsB + rbase * 128);
      gld_lds16((const char*)W + ((size_t)(n0 + row) * 1024 + kt) * 2 + swzb,
                BsB + rbase * 128);
    }
    __syncthreads();

#pragma unroll
    for (int ks = 0; ks < 2; ++ks) {
      const int kpre = ks * 64 + g * 16;
      bf16x8 af[4], bfr[4];
#pragma unroll
      for (int mi = 0; mi < 4; ++mi) {
        int row = wr * 64 + mi * 16 + l15;
        af[mi] = *reinterpret_cast<const bf16x8*>(AsB + row * 128 + (kpre ^ ((row & 7) << 4)));
      }
#pragma unroll
      for (int ni = 0; ni < 4; ++ni) {
        int row = wc * 64 + ni * 16 + l15;
        bfr[ni] = *reinterpret_cast<const bf16x8*>(BsB + row * 128 + (kpre ^ ((row & 7) << 4)));
      }
#pragma unroll
      for (int mi = 0; mi < 4; ++mi)
#pragma unroll
        for (int ni = 0; ni < 4; ++ni)
          acc[mi][ni] = __builtin_amdgcn_mfma_f32_16x16x32_bf16(af[mi], bfr[ni], acc[mi][ni], 0, 0, 0);
    }
    __syncthreads();
  }

  if (z == 2) {
#pragma unroll
    for (int mi = 0; mi < 4; ++mi)
#pragma unroll
      for (int ni = 0; ni < 4; ++ni) {
        int n = n0 + wc * 64 + ni * 16 + l15;
        int h = n >> 6, hd = n & 63;
        int m = m0 + wr * 64 + mi * 16 + 4 * g;
        int b = m >> 11, s0 = m & 2047;
        u16x4 pk = {f2bf(acc[mi][ni][0]), f2bf(acc[mi][ni][1]),
                    f2bf(acc[mi][ni][2]), f2bf(acc[mi][ni][3])};
        *reinterpret_cast<u16x4*>(Out + ((size_t)(b * 16 + h) * 64 + hd) * 2048 + s0) = pk;
      }
  } else {
    const float qs = (z == 0) ? 0.1803368801f : 1.0f;  // 0.125*log2(e)
#pragma unroll
    for (int mi = 0; mi < 4; ++mi)
#pragma unroll
      for (int ni = 0; ni < 4; ++ni)
#pragma unroll
        for (int r = 0; r < 4; ++r) {
          int m = m0 + wr * 64 + mi * 16 + 4 * g + r;
          int n = n0 + wc * 64 + ni * 16 + l15;
          int b = m >> 11, s = m & 2047;
          int h = n >> 6, hd = n & 63;
          Out[((size_t)(b * 16 + h) * 2048 + s) * 64 + hd] = f2bf(acc[mi][ni][r] * qs);
        }
  }
}

// ---------------------------------------------------------------------------
// out projection, bf16 inputs via global_load_lds; fp32 out + bias.
// ---------------------------------------------------------------------------
__global__ __launch_bounds__(256, 3)
void out_proj_b(const unsigned short* __restrict__ Ctx, const unsigned short* __restrict__ Wob,
                const float* __restrict__ Bo, float* __restrict__ Y)
{
  __shared__ __align__(16) unsigned short As[128 * 64];
  __shared__ __align__(16) unsigned short Bs[128 * 64];
  char* AsB = (char*)As;
  char* BsB = (char*)Bs;

  const int flat = blockIdx.x + (blockIdx.y << 3);
  const int swz = (flat & 7) * 64 + (flat >> 3);
  const int n0 = (swz & 7) * 128;
  const int m0 = (swz >> 3) * 128;

  const int t = threadIdx.x;
  const int lane = t & 63, wid = t >> 6;
  const int wr = wid >> 1, wc = wid & 1;
  const int l15 = lane & 15, g = lane >> 4;

  f32x4 acc[4][4] = {};

  for (int kt = 0; kt < 1024; kt += 64) {
#pragma unroll
    for (int i = 0; i < 4; ++i) {
      const int rbase = wid * 32 + i * 8;
      const int row = rbase + (lane >> 3);
      const int swzb = ((lane & 7) * 16) ^ ((row & 7) << 4);
      gld_lds16((const char*)Ctx + ((size_t)(m0 + row) * 1024 + kt) * 2 + swzb,
                AsB + rbase * 128);
      gld_lds16((const char*)Wob + ((size_t)(n0 + row) * 1024 + kt) * 2 + swzb,
                BsB + rbase * 128);
    }
    __syncthreads();

#pragma unroll
    for (int ks = 0; ks < 2; ++ks) {
      const int kpre = ks * 64 + g * 16;
      bf16x8 af[4], bfr[4];
#pragma unroll
      for (int mi = 0; mi < 4; ++mi) {
        int row = wr * 64 + mi * 16 + l15;
        af[mi] = *reinterpret_cast<const bf16x8*>(AsB + row * 128 + (kpre ^ ((row & 7) << 4)));
      }
#pragma unroll
      for (int ni = 0; ni < 4; ++ni) {
        int row = wc * 64 + ni * 16 + l15;
        bfr[ni] = *reinterpret_cast<const bf16x8*>(BsB + row * 128 + (kpre ^ ((row & 7) << 4)));
      }
#pragma unroll
      for (int mi = 0; mi < 4; ++mi)
#pragma unroll
        for (int ni = 0; ni < 4; ++ni)
          acc[mi][ni] = __builtin_amdgcn_mfma_f32_16x16x32_bf16(af[mi], bfr[ni], acc[mi][ni], 0, 0, 0);
    }
    __syncthreads();
  }

#pragma unroll
  for (int mi = 0; mi < 4; ++mi)
#pragma unroll
    for (int ni = 0; ni < 4; ++ni) {
      int n = n0 + wc * 64 + ni * 16 + l15;
      float bias = Bo[n];
#pragma unroll
      for (int r = 0; r < 4; ++r) {
        int m = m0 + wr * 64 + mi * 16 + 4 * g + r;
        Y[(size_t)m * 1024 + n] = acc[mi][ni][r] + bias;
      }
    }
}

// ---------------------------------------------------------------------------
// Causal flash attention: r12 structure (unpaired 1024 blocks, 3/CU,
// tile-major heavy-first, ones-MFMA denominator, perm-pack) with:
//  - manual lgkmcnt/sched_barrier fence REMOVED (compiler orders the P-LDS
//    dependency itself and can overlap V-reads/PV addressing with softmax)
//  - wave-uniform fully-masked-quadrant fast path (write zeros, skip exp)
// ---------------------------------------------------------------------------
__global__ __launch_bounds__(256, 3)
void attn2(const unsigned short* __restrict__ Qb, const unsigned short* __restrict__ Kb,
           const unsigned short* __restrict__ Vtg, unsigned short* __restrict__ Ctx)
{
  __shared__ __align__(16) unsigned short Ks[2][64 * 64];
  __shared__ __align__(16) unsigned short Vts[2][64 * 64];
  __shared__ __align__(16) unsigned short Pl[4][32 * 64];

  const int flat = blockIdx.x;          // 0..1023
  const int xcd = flat & 7;
  const int j = flat >> 3;              // 0..127
  const int tile = 15 - (j >> 3);       // tile-major: all heavy tiles first
  const int bh = xcd * 8 + (j & 7);     // 0..63

  const size_t base = (size_t)bh * (2048 * 64);
  const int t = threadIdx.x;
  const int lane = t & 63, wid = t >> 6;
  const int l15 = lane & 15, g = lane >> 4;
  char* PB = (char*)Pl[wid];
  const int bb = bh >> 4, hh = bh & 15;

  const int sl8 = lane >> 3;
  const int sc8 = lane & 7;
  const int pswz = (l15 & 7) << 4;

  // all-ones A-fragment: mfma(ones, P) accumulates the softmax denominator
  bf16x8 ones;
#pragma unroll
  for (int i = 0; i < 8; ++i) ones[i] = (__bf16)1.0f;

  const int qg0 = tile * 128 + wid * 32;
  const int nst = 2 * tile + 2;

  bf16x8 qf[2][2];
#pragma unroll
  for (int mi = 0; mi < 2; ++mi)
#pragma unroll
    for (int ks = 0; ks < 2; ++ks)
      qf[mi][ks] = *reinterpret_cast<const bf16x8*>(
          Qb + base + (size_t)(qg0 + 16 * mi + l15) * 64 + ks * 32 + g * 8);

  f32x4 o[2][4] = {};
  f32x4 accl[2] = {};

#pragma unroll
  for (int i = 0; i < 2; ++i) {
    int row = wid * 16 + i * 8 + sl8;
    int swzb = (sc8 * 16) ^ ((row & 7) << 4);
    gld_lds16((const char*)Kb + (base + (size_t)row * 64) * 2 + swzb,
              (char*)Ks[0] + (wid * 16 + i * 8) * 128);
    gld_lds16((const char*)Vtg + (base + (size_t)row * 2048) * 2 + swzb,
              (char*)Vts[0] + (wid * 16 + i * 8) * 128);
  }
  __syncthreads();

  int cur = 0;
  for (int s = 0; s < nst; ++s) {
    if (s + 1 < nst) {
#pragma unroll
      for (int i = 0; i < 2; ++i) {
        int row = wid * 16 + i * 8 + sl8;
        int swzb = (sc8 * 16) ^ ((row & 7) << 4);
        gld_lds16((const char*)Kb + (base + (size_t)((s + 1) * 64 + row) * 64) * 2 + swzb,
                  (char*)Ks[cur ^ 1] + (wid * 16 + i * 8) * 128);
        gld_lds16((const char*)Vtg + (base + (size_t)row * 2048 + (s + 1) * 64) * 2 + swzb,
                  (char*)Vts[cur ^ 1] + (wid * 16 + i * 8) * 128);
      }
    }
    char* KsB = (char*)Ks[cur];
    char* VtB = (char*)Vts[cur];

    // ---- swapped QK^T: sw[mi][ni][r] = S[q=16mi+l15][k=16ni+4g+r] ----
    f32x4 sw[2][4] = {};
#pragma unroll
    for (int ks = 0; ks < 2; ++ks) {
      const int kpre = ks * 64 + g * 16;
#pragma unroll
      for (int ni = 0; ni < 4; ++ni) {
        int row = ni * 16 + l15;
        bf16x8 kf = *reinterpret_cast<const bf16x8*>(KsB + row * 128 + (kpre ^ ((row & 7) << 4)));
        sw[0][ni] = __builtin_amdgcn_mfma_f32_16x16x32_bf16(kf, qf[0][ks], sw[0][ni], 0, 0, 0);
        sw[1][ni] = __builtin_amdgcn_mfma_f32_16x16x32_bf16(kf, qf[1][ks], sw[1][ni], 0, 0, 0);
      }
    }

    // ---- fixed-max softmax (exp2 domain) + perm-pack + P write ----
    const bool needmask = (s * 64 + 63 > qg0);
    const int dgl = s * 64 + 4 * g - l15 - qg0;   // k-q = dgl + 16ni - 16mi + r
#pragma unroll
    for (int mi = 0; mi < 2; ++mi) {
#pragma unroll
      for (int ni = 0; ni < 4; ++ni) {
        // wave-uniform fully-masked test: min over lanes/r of (k-q) > 0
        if (needmask && (s * 64 + 16 * (ni - mi) - qg0 - 15 > 0)) {
          uint2 w0 = {0u, 0u};
          *reinterpret_cast<uint2*>(PB + (16 * mi + l15) * 128 + ((32 * ni + 8 * g) ^ pswz)) = w0;
          continue;
        }
        f32x4 v = sw[mi][ni];
        if (needmask) {
          int dbase = dgl + 16 * ni - 16 * mi;
#pragma unroll
          for (int r = 0; r < 4; ++r)
            if (dbase + r > 0) v[r] = -1e30f;
        }
        float p0 = exp2_fast(v[0]);
        float p1 = exp2_fast(v[1]);
        float p2 = exp2_fast(v[2]);
        float p3 = exp2_fast(v[3]);
        uint2 w;
        w.x = pack_bf16(p0, p1);
        w.y = pack_bf16(p2, p3);
        *reinterpret_cast<uint2*>(PB + (16 * mi + l15) * 128 + ((32 * ni + 8 * g) ^ pswz)) = w;
      }
    }
    // (no manual fence: compiler orders P ds_write -> ds_read via lgkmcnt)

    // ---- swapped PV: o += mfma(V^T, P); l via ones-MFMA ----
#pragma unroll
    for (int ks2 = 0; ks2 < 2; ++ks2) {
      const int kpre = ks2 * 64 + g * 16;
      bf16x8 pa0 = *reinterpret_cast<const bf16x8*>(PB + l15 * 128 + (kpre ^ pswz));
      bf16x8 pa1 = *reinterpret_cast<const bf16x8*>(PB + (16 + l15) * 128 + (kpre ^ pswz));
      accl[0] = __builtin_amdgcn_mfma_f32_16x16x32_bf16(ones, pa0, accl[0], 0, 0, 0);
      accl[1] = __builtin_amdgcn_mfma_f32_16x16x32_bf16(ones, pa1, accl[1], 0, 0, 0);
#pragma unroll
      for (int db = 0; db < 4; ++db) {
        int vrow = db * 16 + l15;
        bf16x8 vf = *reinterpret_cast<const bf16x8*>(VtB + vrow * 128 + (kpre ^ ((vrow & 7) << 4)));
        o[0][db] = __builtin_amdgcn_mfma_f32_16x16x32_bf16(vf, pa0, o[0][db], 0, 0, 0);
        o[1][db] = __builtin_amdgcn_mfma_f32_16x16x32_bf16(vf, pa1, o[1][db], 0, 0, 0);
      }
    }
    __syncthreads();
    cur ^= 1;
  }

  // ---- epilogue: l complete per-lane (ones-row MFMA), write ctx ----
#pragma unroll
  for (int mi = 0; mi < 2; ++mi) {
    float inv = 1.0f / accl[mi][0];
    int qg = qg0 + 16 * mi + l15;
#pragma unroll
    for (int db = 0; db < 4; ++db) {
      u16x4 pk = {f2bf(o[mi][db][0] * inv), f2bf(o[mi][db][1] * inv),
                  f2bf(o[mi][db][2] * inv), f2bf(o[mi][db][3] * inv)};
      *reinterpret_cast<u16x4*>(Ctx + ((size_t)(bb * 2048 + qg)) * 1024 + hh * 64 + db * 16 + 4 * g) = pk;
    }
  }
}

// ---------------------------------------------------------------------------
// Fallback kernels (fp32-staged) — used only if ws_size < 72 MiB.
// ---------------------------------------------------------------------------
__global__ __launch_bounds__(256, 2)
void qkv_proj(const float* __restrict__ X,
              const float* __restrict__ Wq, const float* __restrict__ Wk,
              const float* __restrict__ Wv,
              unsigned short* __restrict__ Qb, unsigned short* __restrict__ Kb,
              unsigned short* __restrict__ Vb)
{
  __shared__ __align__(16) unsigned short As[128 * 64];
  __shared__ __align__(16) unsigned short Bs[128 * 64];
  char* AsB = (char*)As;
  char* BsB = (char*)Bs;

  const float* __restrict__ W =
      (blockIdx.z == 0) ? Wq : (blockIdx.z == 1) ? Wk : Wv;
  unsigned short* __restrict__ Out =
      (blockIdx.z == 0) ? Qb : (blockIdx.z == 1) ? Kb : Vb;

  const int m0 = blockIdx.y * 128;
  const int n0 = blockIdx.x * 128;
  const int t = threadIdx.x;
  const int lane = t & 63, wid = t >> 6;
  const int wr = wid >> 1, wc = wid & 1;
  const int l15 = lane & 15, g = lane >> 4;

  f32x4 acc[4][4] = {};

  for (int kt = 0; kt < 1024; kt += 64) {
#pragma unroll
    for (int i = 0; i < 8; ++i) {
      int c = i * 256 + t;
      int row = c >> 4, c4 = c & 15;
      f32x4 a = *reinterpret_cast<const f32x4*>(X + (size_t)(m0 + row) * 1024 + kt + c4 * 4);
      f32x4 b = *reinterpret_cast<const f32x4*>(W + (size_t)(n0 + row) * 1024 + kt + c4 * 4);
      u16x4 va = {f2bf(a.x), f2bf(a.y), f2bf(a.z), f2bf(a.w)};
      u16x4 vb = {f2bf(b.x), f2bf(b.y), f2bf(b.z), f2bf(b.w)};
      int off = row * 128 + ((c4 * 8) ^ ((row & 7) << 4));
      *reinterpret_cast<u16x4*>(AsB + off) = va;
      *reinterpret_cast<u16x4*>(BsB + off) = vb;
    }
    __syncthreads();

#pragma unroll
    for (int ks = 0; ks < 2; ++ks) {
      const int kpre = ks * 64 + g * 16;
      bf16x8 af[4], bfr[4];
#pragma unroll
      for (int mi = 0; mi < 4; ++mi) {
        int row = wr * 64 + mi * 16 + l15;
        af[mi] = *reinterpret_cast<const bf16x8*>(AsB + row * 128 + (kpre ^ ((row & 7) << 4)));
      }
#pragma unroll
      for (int ni = 0; ni < 4; ++ni) {
        int row = wc * 64 + ni * 16 + l15;
        bfr[ni] = *reinterpret_cast<const bf16x8*>(BsB + row * 128 + (kpre ^ ((row & 7) << 4)));
      }
#pragma unroll
      for (int mi = 0; mi < 4; ++mi)
#pragma unroll
        for (int ni = 0; ni < 4; ++ni)
          acc[mi][ni] = __builtin_amdgcn_mfma_f32_16x16x32_bf16(af[mi], bfr[ni], acc[mi][ni], 0, 0, 0);
    }
    __syncthreads();
  }

  if (blockIdx.z == 2) {
#pragma unroll
    for (int mi = 0; mi < 4; ++mi)
#pragma unroll
      for (int ni = 0; ni < 4; ++ni) {
        int n = n0 + wc * 64 + ni * 16 + l15;
        int h = n >> 6, hd = n & 63;
        int m = m0 + wr * 64 + mi * 16 + 4 * g;
        int b = m >> 11, s0 = m & 2047;
        u16x4 pk = {f2bf(acc[mi][ni][0]), f2bf(acc[mi][ni][1]),
                    f2bf(acc[mi][ni][2]), f2bf(acc[mi][ni][3])};
        *reinterpret_cast<u16x4*>(Out + ((size_t)(b * 16 + h) * 64 + hd) * 2048 + s0) = pk;
      }
  } else {
    const float qs = (blockIdx.z == 0) ? 0.1803368801f : 1.0f;
#pragma unroll
    for (int mi = 0; mi < 4; ++mi)
#pragma unroll
      for (int ni = 0; ni < 4; ++ni)
#pragma unroll
        for (int r = 0; r < 4; ++r) {
          int m = m0 + wr * 64 + mi * 16 + 4 * g + r;
          int n = n0 + wc * 64 + ni * 16 + l15;
          int b = m >> 11, s = m & 2047;
          int h = n >> 6, hd = n & 63;
          Out[((size_t)(b * 16 + h) * 2048 + s) * 64 + hd] = f2bf(acc[mi][ni][r] * qs);
        }
  }
}

__global__ __launch_bounds__(256, 2)
void out_proj(const unsigned short* __restrict__ Ctx, const float* __restrict__ Wo,
              const float* __restrict__ Bo, float* __restrict__ Y)
{
  __shared__ __align__(16) unsigned short As[128 * 64];
  __shared__ __align__(16) unsigned short Bs[128 * 64];
  char* AsB = (char*)As;
  char* BsB = (char*)Bs;

  const int m0 = blockIdx.y * 128;
  const int n0 = blockIdx.x * 128;
  const int t = threadIdx.x;
  const int lane = t & 63, wid = t >> 6;
  const int wr = wid >> 1, wc = wid & 1;
  const int l15 = lane & 15, g = lane >> 4;

  f32x4 acc[4][4] = {};

  for (int kt = 0; kt < 1024; kt += 64) {
#pragma unroll
    for (int i = 0; i < 4; ++i) {
      int c = i * 256 + t;
      int row = c >> 3, c8 = c & 7;
      bf16x8 v = *reinterpret_cast<const bf16x8*>(Ctx + (size_t)(m0 + row) * 1024 + kt + c8 * 8);
      *reinterpret_cast<bf16x8*>(AsB + row * 128 + ((c8 * 16) ^ ((row & 7) << 4))) = v;
    }
#pragma unroll
    for (int i = 0; i < 8; ++i) {
      int c = i * 256 + t;
      int row = c >> 4, c4 = c & 15;
      f32x4 b = *reinterpret_cast<const f32x4*>(Wo + (size_t)(n0 + row) * 1024 + kt + c4 * 4);
      u16x4 vb = {f2bf(b.x), f2bf(b.y), f2bf(b.z), f2bf(b.w)};
      *reinterpret_cast<u16x4*>(BsB + row * 128 + ((c4 * 8) ^ ((row & 7) << 4))) = vb;
    }
    __syncthreads();

#pragma unroll
    for (int ks = 0; ks < 2; ++ks) {
      const int kpre = ks * 64 + g * 16;
      bf16x8 af[4], bfr[4];
#pragma unroll
      for (int mi = 0; mi < 4; ++mi) {
        int row = wr * 64 + mi * 16 + l15;
        af[mi] = *reinterpret_cast<const bf16x8*>(AsB + row * 128 + (kpre ^ ((row & 7) << 4)));
      }
#pragma unroll
      for (int ni = 0; ni < 4; ++ni) {
        int row = wc * 64 + ni * 16 + l15;
        bfr[ni] = *reinterpret_cast<const bf16x8*>(BsB + row * 128 + (kpre ^ ((row & 7) << 4)));
      }
#pragma unroll
      for (int mi = 0; mi < 4; ++mi)
#pragma unroll
        for (int ni = 0; ni < 4; ++ni)
          acc[mi][ni] = __builtin_amdgcn_mfma_f32_16x16x32_bf16(af[mi], bfr[ni], acc[mi][ni], 0, 0, 0);
    }
    __syncthreads();
  }

#pragma unroll
  for (int mi = 0; mi < 4; ++mi)
#pragma unroll
    for (int ni = 0; ni < 4; ++ni) {
      int n = n0 + wc * 64 + ni * 16 + l15;
      float bias = Bo[n];
#pragma unroll
      for (int r = 0; r < 4; ++r) {
        int m = m0 + wr * 64 + mi * 16 + 4 * g + r;
        Y[(size_t)m * 1024 + n] = acc[mi][ni][r] + bias;
      }
    }
}

// ---------------------------------------------------------------------------
extern "C" void kernel_launch(void* const* d_in, const int* in_sizes, int n_in,
                              void* d_out, int out_size, void* d_ws, size_t ws_size,
                              hipStream_t stream)
{
  const float* x  = (const float*)d_in[0];
  const float* wq = (const float*)d_in[1];
  const float* wk = (const float*)d_in[2];
  const float* wv = (const float*)d_in[3];
  const float* wo = (const float*)d_in[4];
  const float* bo = (const float*)d_in[5];
  float* y = (float*)d_out;

  if (ws_size >= 75497472ULL) {
    // fast path: [Xb|Cx 16Mi][Qb 16Mi][Kb 16Mi][Vb 16Mi][Wq,Wk,Wv,Wo bf16 8Mi]
    unsigned short* Xb = (unsigned short*)d_ws;   // aliased by Cx after qkv
    unsigned short* Qb = Xb + 8388608;
    unsigned short* Kb = Qb + 8388608;
    unsigned short* Vb = Kb + 8388608;
    unsigned short* Wb = Vb + 8388608;            // 4 x 1048576 bf16
    unsigned short* Cx = Xb;

    cvt_bf16<<<6144, 256, 0, stream>>>(x, wq, wk, wv, wo, Xb, Wb);
    qkv_proj_b<<<dim3(8, 64, 3), 256, 0, stream>>>(Xb, Wb, Qb, Kb, Vb);
    attn2<<<1024, 256, 0, stream>>>(Qb, Kb, Vb, Cx);
    out_proj_b<<<dim3(8, 64), 256, 0, stream>>>(Cx, Wb + 3 * 1048576, bo, y);
  } else {
    // fallback: fp32-staged GEMMs + same attention
    unsigned short* Qb = (unsigned short*)d_ws;
    unsigned short* Kb = Qb + 8388608;
    unsigned short* Vb = Kb + 8388608;
    unsigned short* Cx = Vb + 8388608;

    qkv_proj<<<dim3(8, 64, 3), 256, 0, stream>>>(x, wq, wk, wv, Qb, Kb, Vb);
    attn2<<<1024, 256, 0, stream>>>(Qb, Kb, Vb, Cx);
    out_proj<<<dim3(8, 64), 256, 0, stream>>>(Cx, wo, bo, y);
  }
}

// Round 14
// 149.725 us; speedup vs baseline: 1.0407x; 1.0407x over previous
//
#include <hip/hip_runtime.h>
#include <hip/hip_bf16.h>

typedef __bf16 bf16x8 __attribute__((ext_vector_type(8)));
typedef float f32x4 __attribute__((ext_vector_type(4)));
typedef unsigned short u16x4 __attribute__((ext_vector_type(4)));
typedef unsigned short u16x8 __attribute__((ext_vector_type(8)));

__device__ __forceinline__ unsigned short f2bf(float f) {
  unsigned int u = __float_as_uint(f);
  u += 0x7FFFu + ((u >> 16) & 1u);   // round-to-nearest-even
  return (unsigned short)(u >> 16);
}

__device__ __forceinline__ float exp2_fast(float x) {
  return __builtin_amdgcn_exp2f(x);   // v_exp_f32
}

// pack two fp32 -> two bf16 (truncating) in one v_perm_b32
__device__ __forceinline__ unsigned pack_bf16(float lo, float hi) {
  return __builtin_amdgcn_perm(__float_as_uint(hi), __float_as_uint(lo), 0x07060302u);
}

// async global->LDS, 16B per lane; LDS dest = wave-uniform base + lane*16
__device__ __forceinline__ void gld_lds16(const void* g, void* l) {
  __builtin_amdgcn_global_load_lds(
      (__attribute__((address_space(1))) void*)g,
      (__attribute__((address_space(3))) void*)l,
      16, 0, 0);
}

// ---------------------------------------------------------------------------
// fp32 -> bf16 conversion pre-pass: X (8.4M elems) + Wq,Wk,Wv,Wo (1M each).
// ---------------------------------------------------------------------------
__global__ __launch_bounds__(256)
void cvt_bf16(const float* __restrict__ x, const float* __restrict__ wq,
              const float* __restrict__ wk, const float* __restrict__ wv,
              const float* __restrict__ wo,
              unsigned short* __restrict__ Xb, unsigned short* __restrict__ Wb)
{
  unsigned c = blockIdx.x * 256 + threadIdx.x;
  const float* src;
  unsigned short* dst;
  unsigned off;
  if (c < 1048576u) {               // X: 1048576 chunks
    src = x; dst = Xb; off = c;
  } else {                          // W's: 131072 chunks each
    unsigned cc = c - 1048576u;
    unsigned which = cc >> 17;
    off = cc & 131071u;
    src = which == 0 ? wq : which == 1 ? wk : which == 2 ? wv : wo;
    dst = Wb + (size_t)which * 1048576u;
  }
  f32x4 a = *reinterpret_cast<const f32x4*>(src + (size_t)off * 8);
  f32x4 b = *reinterpret_cast<const f32x4*>(src + (size_t)off * 8 + 4);
  u16x8 o = {f2bf(a.x), f2bf(a.y), f2bf(a.z), f2bf(a.w),
             f2bf(b.x), f2bf(b.y), f2bf(b.z), f2bf(b.w)};
  *reinterpret_cast<u16x8*>(dst + (size_t)off * 8) = o;
}

// ---------------------------------------------------------------------------
// bf16 GEMM C[m,n] = sum_k A[m,k]*W[n,k] via global_load_lds staging.
// ---------------------------------------------------------------------------
__global__ __launch_bounds__(256, 3)
void qkv_proj_b(const unsigned short* __restrict__ Xb, const unsigned short* __restrict__ Wb,
                unsigned short* __restrict__ Qb, unsigned short* __restrict__ Kb,
                unsigned short* __restrict__ Vb)
{
  __shared__ __align__(16) unsigned short As[128 * 64];
  __shared__ __align__(16) unsigned short Bs[128 * 64];
  char* AsB = (char*)As;
  char* BsB = (char*)Bs;

  const int z = blockIdx.z;
  const unsigned short* __restrict__ W = Wb + (size_t)z * 1048576u;
  unsigned short* __restrict__ Out = (z == 0) ? Qb : (z == 1) ? Kb : Vb;

  const int flat = blockIdx.x + (blockIdx.y << 3);
  const int swz = (flat & 7) * 64 + (flat >> 3);
  const int n0 = (swz & 7) * 128;
  const int m0 = (swz >> 3) * 128;

  const int t = threadIdx.x;
  const int lane = t & 63, wid = t >> 6;
  const int wr = wid >> 1, wc = wid & 1;
  const int l15 = lane & 15, g = lane >> 4;

  f32x4 acc[4][4] = {};

  for (int kt = 0; kt < 1024; kt += 64) {
#pragma unroll
    for (int i = 0; i < 4; ++i) {
      const int rbase = wid * 32 + i * 8;
      const int row = rbase + (lane >> 3);
      const int swzb = ((lane & 7) * 16) ^ ((row & 7) << 4);
      gld_lds16((const char*)Xb + ((size_t)(m0 + row) * 1024 + kt) * 2 + swzb,
                AsB + rbase * 128);
      gld_lds16((const char*)W + ((size_t)(n0 + row) * 1024 + kt) * 2 + swzb,
                BsB + rbase * 128);
    }
    __syncthreads();

#pragma unroll
    for (int ks = 0; ks < 2; ++ks) {
      const int kpre = ks * 64 + g * 16;
      bf16x8 af[4], bfr[4];
#pragma unroll
      for (int mi = 0; mi < 4; ++mi) {
        int row = wr * 64 + mi * 16 + l15;
        af[mi] = *reinterpret_cast<const bf16x8*>(AsB + row * 128 + (kpre ^ ((row & 7) << 4)));
      }
#pragma unroll
      for (int ni = 0; ni < 4; ++ni) {
        int row = wc * 64 + ni * 16 + l15;
        bfr[ni] = *reinterpret_cast<const bf16x8*>(BsB + row * 128 + (kpre ^ ((row & 7) << 4)));
      }
#pragma unroll
      for (int mi = 0; mi < 4; ++mi)
#pragma unroll
        for (int ni = 0; ni < 4; ++ni)
          acc[mi][ni] = __builtin_amdgcn_mfma_f32_16x16x32_bf16(af[mi], bfr[ni], acc[mi][ni], 0, 0, 0);
    }
    __syncthreads();
  }

  if (z == 2) {
#pragma unroll
    for (int mi = 0; mi < 4; ++mi)
#pragma unroll
      for (int ni = 0; ni < 4; ++ni) {
        int n = n0 + wc * 64 + ni * 16 + l15;
        int h = n >> 6, hd = n & 63;
        int m = m0 + wr * 64 + mi * 16 + 4 * g;
        int b = m >> 11, s0 = m & 2047;
        u16x4 pk = {f2bf(acc[mi][ni][0]), f2bf(acc[mi][ni][1]),
                    f2bf(acc[mi][ni][2]), f2bf(acc[mi][ni][3])};
        *reinterpret_cast<u16x4*>(Out + ((size_t)(b * 16 + h) * 64 + hd) * 2048 + s0) = pk;
      }
  } else {
    const float qs = (z == 0) ? 0.1803368801f : 1.0f;  // 0.125*log2(e)
#pragma unroll
    for (int mi = 0; mi < 4; ++mi)
#pragma unroll
      for (int ni = 0; ni < 4; ++ni)
#pragma unroll
        for (int r = 0; r < 4; ++r) {
          int m = m0 + wr * 64 + mi * 16 + 4 * g + r;
          int n = n0 + wc * 64 + ni * 16 + l15;
          int b = m >> 11, s = m & 2047;
          int h = n >> 6, hd = n & 63;
          Out[((size_t)(b * 16 + h) * 2048 + s) * 64 + hd] = f2bf(acc[mi][ni][r] * qs);
        }
  }
}

// ---------------------------------------------------------------------------
// out projection, bf16 inputs via global_load_lds; fp32 out + bias.
// ---------------------------------------------------------------------------
__global__ __launch_bounds__(256, 3)
void out_proj_b(const unsigned short* __restrict__ Ctx, const unsigned short* __restrict__ Wob,
                const float* __restrict__ Bo, float* __restrict__ Y)
{
  __shared__ __align__(16) unsigned short As[128 * 64];
  __shared__ __align__(16) unsigned short Bs[128 * 64];
  char* AsB = (char*)As;
  char* BsB = (char*)Bs;

  const int flat = blockIdx.x + (blockIdx.y << 3);
  const int swz = (flat & 7) * 64 + (flat >> 3);
  const int n0 = (swz & 7) * 128;
  const int m0 = (swz >> 3) * 128;

  const int t = threadIdx.x;
  const int lane = t & 63, wid = t >> 6;
  const int wr = wid >> 1, wc = wid & 1;
  const int l15 = lane & 15, g = lane >> 4;

  f32x4 acc[4][4] = {};

  for (int kt = 0; kt < 1024; kt += 64) {
#pragma unroll
    for (int i = 0; i < 4; ++i) {
      const int rbase = wid * 32 + i * 8;
      const int row = rbase + (lane >> 3);
      const int swzb = ((lane & 7) * 16) ^ ((row & 7) << 4);
      gld_lds16((const char*)Ctx + ((size_t)(m0 + row) * 1024 + kt) * 2 + swzb,
                AsB + rbase * 128);
      gld_lds16((const char*)Wob + ((size_t)(n0 + row) * 1024 + kt) * 2 + swzb,
                BsB + rbase * 128);
    }
    __syncthreads();

#pragma unroll
    for (int ks = 0; ks < 2; ++ks) {
      const int kpre = ks * 64 + g * 16;
      bf16x8 af[4], bfr[4];
#pragma unroll
      for (int mi = 0; mi < 4; ++mi) {
        int row = wr * 64 + mi * 16 + l15;
        af[mi] = *reinterpret_cast<const bf16x8*>(AsB + row * 128 + (kpre ^ ((row & 7) << 4)));
      }
#pragma unroll
      for (int ni = 0; ni < 4; ++ni) {
        int row = wc * 64 + ni * 16 + l15;
        bfr[ni] = *reinterpret_cast<const bf16x8*>(BsB + row * 128 + (kpre ^ ((row & 7) << 4)));
      }
#pragma unroll
      for (int mi = 0; mi < 4; ++mi)
#pragma unroll
        for (int ni = 0; ni < 4; ++ni)
          acc[mi][ni] = __builtin_amdgcn_mfma_f32_16x16x32_bf16(af[mi], bfr[ni], acc[mi][ni], 0, 0, 0);
    }
    __syncthreads();
  }

#pragma unroll
  for (int mi = 0; mi < 4; ++mi)
#pragma unroll
    for (int ni = 0; ni < 4; ++ni) {
      int n = n0 + wc * 64 + ni * 16 + l15;
      float bias = Bo[n];
#pragma unroll
      for (int r = 0; r < 4; ++r) {
        int m = m0 + wr * 64 + mi * 16 + 4 * g + r;
        Y[(size_t)m * 1024 + n] = acc[mi][ni][r] + bias;
      }
    }
}

// ---------------------------------------------------------------------------
// Causal flash attention (r12 exact): unpaired 1024 blocks, one 128-row
// q-tile each, tile-major heavy-first per XCD strip, 48KB LDS -> 3 blocks/CU.
// Swapped QK^T, fixed-max exp2 softmax (zero cross-lane), perm-pack P,
// ones-MFMA denominator, fence after P-writes (load-bearing per r13 A/B).
// ---------------------------------------------------------------------------
__global__ __launch_bounds__(256, 3)
void attn2(const unsigned short* __restrict__ Qb, const unsigned short* __restrict__ Kb,
           const unsigned short* __restrict__ Vtg, unsigned short* __restrict__ Ctx)
{
  __shared__ __align__(16) unsigned short Ks[2][64 * 64];
  __shared__ __align__(16) unsigned short Vts[2][64 * 64];
  __shared__ __align__(16) unsigned short Pl[4][32 * 64];

  const int flat = blockIdx.x;          // 0..1023
  const int xcd = flat & 7;
  const int j = flat >> 3;              // 0..127
  const int tile = 15 - (j >> 3);       // tile-major: all heavy tiles first
  const int bh = xcd * 8 + (j & 7);     // 0..63

  const size_t base = (size_t)bh * (2048 * 64);
  const int t = threadIdx.x;
  const int lane = t & 63, wid = t >> 6;
  const int l15 = lane & 15, g = lane >> 4;
  char* PB = (char*)Pl[wid];
  const int bb = bh >> 4, hh = bh & 15;

  const int sl8 = lane >> 3;
  const int sc8 = lane & 7;
  const int pswz = (l15 & 7) << 4;

  // all-ones A-fragment: mfma(ones, P) accumulates the softmax denominator
  bf16x8 ones;
#pragma unroll
  for (int i = 0; i < 8; ++i) ones[i] = (__bf16)1.0f;

  const int qg0 = tile * 128 + wid * 32;
  const int nst = 2 * tile + 2;

  bf16x8 qf[2][2];
#pragma unroll
  for (int mi = 0; mi < 2; ++mi)
#pragma unroll
    for (int ks = 0; ks < 2; ++ks)
      qf[mi][ks] = *reinterpret_cast<const bf16x8*>(
          Qb + base + (size_t)(qg0 + 16 * mi + l15) * 64 + ks * 32 + g * 8);

  f32x4 o[2][4] = {};
  f32x4 accl[2] = {};

#pragma unroll
  for (int i = 0; i < 2; ++i) {
    int row = wid * 16 + i * 8 + sl8;
    int swzb = (sc8 * 16) ^ ((row & 7) << 4);
    gld_lds16((const char*)Kb + (base + (size_t)row * 64) * 2 + swzb,
              (char*)Ks[0] + (wid * 16 + i * 8) * 128);
    gld_lds16((const char*)Vtg + (base + (size_t)row * 2048) * 2 + swzb,
              (char*)Vts[0] + (wid * 16 + i * 8) * 128);
  }
  __syncthreads();

  int cur = 0;
  for (int s = 0; s < nst; ++s) {
    if (s + 1 < nst) {
#pragma unroll
      for (int i = 0; i < 2; ++i) {
        int row = wid * 16 + i * 8 + sl8;
        int swzb = (sc8 * 16) ^ ((row & 7) << 4);
        gld_lds16((const char*)Kb + (base + (size_t)((s + 1) * 64 + row) * 64) * 2 + swzb,
                  (char*)Ks[cur ^ 1] + (wid * 16 + i * 8) * 128);
        gld_lds16((const char*)Vtg + (base + (size_t)row * 2048 + (s + 1) * 64) * 2 + swzb,
                  (char*)Vts[cur ^ 1] + (wid * 16 + i * 8) * 128);
      }
    }
    char* KsB = (char*)Ks[cur];
    char* VtB = (char*)Vts[cur];

    // ---- swapped QK^T: sw[mi][ni][r] = S[q=16mi+l15][k=16ni+4g+r] ----
    f32x4 sw[2][4] = {};
#pragma unroll
    for (int ks = 0; ks < 2; ++ks) {
      const int kpre = ks * 64 + g * 16;
#pragma unroll
      for (int ni = 0; ni < 4; ++ni) {
        int row = ni * 16 + l15;
        bf16x8 kf = *reinterpret_cast<const bf16x8*>(KsB + row * 128 + (kpre ^ ((row & 7) << 4)));
        sw[0][ni] = __builtin_amdgcn_mfma_f32_16x16x32_bf16(kf, qf[0][ks], sw[0][ni], 0, 0, 0);
        sw[1][ni] = __builtin_amdgcn_mfma_f32_16x16x32_bf16(kf, qf[1][ks], sw[1][ni], 0, 0, 0);
      }
    }

    // ---- fixed-max softmax (exp2 domain) + perm-pack + P write ----
    const bool needmask = (s * 64 + 63 > qg0);
    const int dgl = s * 64 + 4 * g - l15 - qg0;   // k-q = dgl + 16ni - 16mi + r
#pragma unroll
    for (int mi = 0; mi < 2; ++mi) {
#pragma unroll
      for (int ni = 0; ni < 4; ++ni) {
        f32x4 v = sw[mi][ni];
        if (needmask) {
          int dbase = dgl + 16 * ni - 16 * mi;
#pragma unroll
          for (int r = 0; r < 4; ++r)
            if (dbase + r > 0) v[r] = -1e30f;
        }
        float p0 = exp2_fast(v[0]);
        float p1 = exp2_fast(v[1]);
        float p2 = exp2_fast(v[2]);
        float p3 = exp2_fast(v[3]);
        uint2 w;
        w.x = pack_bf16(p0, p1);
        w.y = pack_bf16(p2, p3);
        *reinterpret_cast<uint2*>(PB + (16 * mi + l15) * 128 + ((32 * ni + 8 * g) ^ pswz)) = w;
      }
    }
    asm volatile("s_waitcnt lgkmcnt(0)" ::: "memory");
    __builtin_amdgcn_sched_barrier(0);

    // ---- swapped PV: o += mfma(V^T, P); l via ones-MFMA ----
#pragma unroll
    for (int ks2 = 0; ks2 < 2; ++ks2) {
      const int kpre = ks2 * 64 + g * 16;
      bf16x8 pa0 = *reinterpret_cast<const bf16x8*>(PB + l15 * 128 + (kpre ^ pswz));
      bf16x8 pa1 = *reinterpret_cast<const bf16x8*>(PB + (16 + l15) * 128 + (kpre ^ pswz));
      accl[0] = __builtin_amdgcn_mfma_f32_16x16x32_bf16(ones, pa0, accl[0], 0, 0, 0);
      accl[1] = __builtin_amdgcn_mfma_f32_16x16x32_bf16(ones, pa1, accl[1], 0, 0, 0);
#pragma unroll
      for (int db = 0; db < 4; ++db) {
        int vrow = db * 16 + l15;
        bf16x8 vf = *reinterpret_cast<const bf16x8*>(VtB + vrow * 128 + (kpre ^ ((vrow & 7) << 4)));
        o[0][db] = __builtin_amdgcn_mfma_f32_16x16x32_bf16(vf, pa0, o[0][db], 0, 0, 0);
        o[1][db] = __builtin_amdgcn_mfma_f32_16x16x32_bf16(vf, pa1, o[1][db], 0, 0, 0);
      }
    }
    __syncthreads();
    cur ^= 1;
  }

  // ---- epilogue: l complete per-lane (ones-row MFMA), write ctx ----
#pragma unroll
  for (int mi = 0; mi < 2; ++mi) {
    float inv = 1.0f / accl[mi][0];
    int qg = qg0 + 16 * mi + l15;
#pragma unroll
    for (int db = 0; db < 4; ++db) {
      u16x4 pk = {f2bf(o[mi][db][0] * inv), f2bf(o[mi][db][1] * inv),
                  f2bf(o[mi][db][2] * inv), f2bf(o[mi][db][3] * inv)};
      *reinterpret_cast<u16x4*>(Ctx + ((size_t)(bb * 2048 + qg)) * 1024 + hh * 64 + db * 16 + 4 * g) = pk;
    }
  }
}

// ---------------------------------------------------------------------------
// Fallback kernels (fp32-staged) — used only if ws_size < 72 MiB.
// ---------------------------------------------------------------------------
__global__ __launch_bounds__(256, 2)
void qkv_proj(const float* __restrict__ X,
              const float* __restrict__ Wq, const float* __restrict__ Wk,
              const float* __restrict__ Wv,
              unsigned short* __restrict__ Qb, unsigned short* __restrict__ Kb,
              unsigned short* __restrict__ Vb)
{
  __shared__ __align__(16) unsigned short As[128 * 64];
  __shared__ __align__(16) unsigned short Bs[128 * 64];
  char* AsB = (char*)As;
  char* BsB = (char*)Bs;

  const float* __restrict__ W =
      (blockIdx.z == 0) ? Wq : (blockIdx.z == 1) ? Wk : Wv;
  unsigned short* __restrict__ Out =
      (blockIdx.z == 0) ? Qb : (blockIdx.z == 1) ? Kb : Vb;

  const int m0 = blockIdx.y * 128;
  const int n0 = blockIdx.x * 128;
  const int t = threadIdx.x;
  const int lane = t & 63, wid = t >> 6;
  const int wr = wid >> 1, wc = wid & 1;
  const int l15 = lane & 15, g = lane >> 4;

  f32x4 acc[4][4] = {};

  for (int kt = 0; kt < 1024; kt += 64) {
#pragma unroll
    for (int i = 0; i < 8; ++i) {
      int c = i * 256 + t;
      int row = c >> 4, c4 = c & 15;
      f32x4 a = *reinterpret_cast<const f32x4*>(X + (size_t)(m0 + row) * 1024 + kt + c4 * 4);
      f32x4 b = *reinterpret_cast<const f32x4*>(W + (size_t)(n0 + row) * 1024 + kt + c4 * 4);
      u16x4 va = {f2bf(a.x), f2bf(a.y), f2bf(a.z), f2bf(a.w)};
      u16x4 vb = {f2bf(b.x), f2bf(b.y), f2bf(b.z), f2bf(b.w)};
      int off = row * 128 + ((c4 * 8) ^ ((row & 7) << 4));
      *reinterpret_cast<u16x4*>(AsB + off) = va;
      *reinterpret_cast<u16x4*>(BsB + off) = vb;
    }
    __syncthreads();

#pragma unroll
    for (int ks = 0; ks < 2; ++ks) {
      const int kpre = ks * 64 + g * 16;
      bf16x8 af[4], bfr[4];
#pragma unroll
      for (int mi = 0; mi < 4; ++mi) {
        int row = wr * 64 + mi * 16 + l15;
        af[mi] = *reinterpret_cast<const bf16x8*>(AsB + row * 128 + (kpre ^ ((row & 7) << 4)));
      }
#pragma unroll
      for (int ni = 0; ni < 4; ++ni) {
        int row = wc * 64 + ni * 16 + l15;
        bfr[ni] = *reinterpret_cast<const bf16x8*>(BsB + row * 128 + (kpre ^ ((row & 7) << 4)));
      }
#pragma unroll
      for (int mi = 0; mi < 4; ++mi)
#pragma unroll
        for (int ni = 0; ni < 4; ++ni)
          acc[mi][ni] = __builtin_amdgcn_mfma_f32_16x16x32_bf16(af[mi], bfr[ni], acc[mi][ni], 0, 0, 0);
    }
    __syncthreads();
  }

  if (blockIdx.z == 2) {
#pragma unroll
    for (int mi = 0; mi < 4; ++mi)
#pragma unroll
      for (int ni = 0; ni < 4; ++ni) {
        int n = n0 + wc * 64 + ni * 16 + l15;
        int h = n >> 6, hd = n & 63;
        int m = m0 + wr * 64 + mi * 16 + 4 * g;
        int b = m >> 11, s0 = m & 2047;
        u16x4 pk = {f2bf(acc[mi][ni][0]), f2bf(acc[mi][ni][1]),
                    f2bf(acc[mi][ni][2]), f2bf(acc[mi][ni][3])};
        *reinterpret_cast<u16x4*>(Out + ((size_t)(b * 16 + h) * 64 + hd) * 2048 + s0) = pk;
      }
  } else {
    const float qs = (blockIdx.z == 0) ? 0.1803368801f : 1.0f;
#pragma unroll
    for (int mi = 0; mi < 4; ++mi)
#pragma unroll
      for (int ni = 0; ni < 4; ++ni)
#pragma unroll
        for (int r = 0; r < 4; ++r) {
          int m = m0 + wr * 64 + mi * 16 + 4 * g + r;
          int n = n0 + wc * 64 + ni * 16 + l15;
          int b = m >> 11, s = m & 2047;
          int h = n >> 6, hd = n & 63;
          Out[((size_t)(b * 16 + h) * 2048 + s) * 64 + hd] = f2bf(acc[mi][ni][r] * qs);
        }
  }
}

__global__ __launch_bounds__(256, 2)
void out_proj(const unsigned short* __restrict__ Ctx, const float* __restrict__ Wo,
              const float* __restrict__ Bo, float* __restrict__ Y)
{
  __shared__ __align__(16) unsigned short As[128 * 64];
  __shared__ __align__(16) unsigned short Bs[128 * 64];
  char* AsB = (char*)As;
  char* BsB = (char*)Bs;

  const int m0 = blockIdx.y * 128;
  const int n0 = blockIdx.x * 128;
  const int t = threadIdx.x;
  const int lane = t & 63, wid = t >> 6;
  const int wr = wid >> 1, wc = wid & 1;
  const int l15 = lane & 15, g = lane >> 4;

  f32x4 acc[4][4] = {};

  for (int kt = 0; kt < 1024; kt += 64) {
#pragma unroll
    for (int i = 0; i < 4; ++i) {
      int c = i * 256 + t;
      int row = c >> 3, c8 = c & 7;
      bf16x8 v = *reinterpret_cast<const bf16x8*>(Ctx + (size_t)(m0 + row) * 1024 + kt + c8 * 8);
      *reinterpret_cast<bf16x8*>(AsB + row * 128 + ((c8 * 16) ^ ((row & 7) << 4))) = v;
    }
#pragma unroll
    for (int i = 0; i < 8; ++i) {
      int c = i * 256 + t;
      int row = c >> 4, c4 = c & 15;
      f32x4 b = *reinterpret_cast<const f32x4*>(Wo + (size_t)(n0 + row) * 1024 + kt + c4 * 4);
      u16x4 vb = {f2bf(b.x), f2bf(b.y), f2bf(b.z), f2bf(b.w)};
      *reinterpret_cast<u16x4*>(BsB + row * 128 + ((c4 * 8) ^ ((row & 7) << 4))) = vb;
    }
    __syncthreads();

#pragma unroll
    for (int ks = 0; ks < 2; ++ks) {
      const int kpre = ks * 64 + g * 16;
      bf16x8 af[4], bfr[4];
#pragma unroll
      for (int mi = 0; mi < 4; ++mi) {
        int row = wr * 64 + mi * 16 + l15;
        af[mi] = *reinterpret_cast<const bf16x8*>(AsB + row * 128 + (kpre ^ ((row & 7) << 4)));
      }
#pragma unroll
      for (int ni = 0; ni < 4; ++ni) {
        int row = wc * 64 + ni * 16 + l15;
        bfr[ni] = *reinterpret_cast<const bf16x8*>(BsB + row * 128 + (kpre ^ ((row & 7) << 4)));
      }
#pragma unroll
      for (int mi = 0; mi < 4; ++mi)
#pragma unroll
        for (int ni = 0; ni < 4; ++ni)
          acc[mi][ni] = __builtin_amdgcn_mfma_f32_16x16x32_bf16(af[mi], bfr[ni], acc[mi][ni], 0, 0, 0);
    }
    __syncthreads();
  }

#pragma unroll
  for (int mi = 0; mi < 4; ++mi)
#pragma unroll
    for (int ni = 0; ni < 4; ++ni) {
      int n = n0 + wc * 64 + ni * 16 + l15;
      float bias = Bo[n];
#pragma unroll
      for (int r = 0; r < 4; ++r) {
        int m = m0 + wr * 64 + mi * 16 + 4 * g + r;
        Y[(size_t)m * 1024 + n] = acc[mi][ni][r] + bias;
      }
    }
}

// ---------------------------------------------------------------------------
extern "C" void kernel_launch(void* const* d_in, const int* in_sizes, int n_in,
                              void* d_out, int out_size, void* d_ws, size_t ws_size,
                              hipStream_t stream)
{
  const float* x  = (const float*)d_in[0];
  const float* wq = (const float*)d_in[1];
  const float* wk = (const float*)d_in[2];
  const float* wv = (const float*)d_in[3];
  const float* wo = (const float*)d_in[4];
  const float* bo = (const float*)d_in[5];
  float* y = (float*)d_out;

  if (ws_size >= 75497472ULL) {
    // fast path: [Xb|Cx 16Mi][Qb 16Mi][Kb 16Mi][Vb 16Mi][Wq,Wk,Wv,Wo bf16 8Mi]
    unsigned short* Xb = (unsigned short*)d_ws;   // aliased by Cx after qkv
    unsigned short* Qb = Xb + 8388608;
    unsigned short* Kb = Qb + 8388608;
    unsigned short* Vb = Kb + 8388608;
    unsigned short* Wb = Vb + 8388608;            // 4 x 1048576 bf16
    unsigned short* Cx = Xb;

    cvt_bf16<<<6144, 256, 0, stream>>>(x, wq, wk, wv, wo, Xb, Wb);
    qkv_proj_b<<<dim3(8, 64, 3), 256, 0, stream>>>(Xb, Wb, Qb, Kb, Vb);
    attn2<<<1024, 256, 0, stream>>>(Qb, Kb, Vb, Cx);
    out_proj_b<<<dim3(8, 64), 256, 0, stream>>>(Cx, Wb + 3 * 1048576, bo, y);
  } else {
    // fallback: fp32-staged GEMMs + same attention
    unsigned short* Qb = (unsigned short*)d_ws;
    unsigned short* Kb = Qb + 8388608;
    unsigned short* Vb = Kb + 8388608;
    unsigned short* Cx = Vb + 8388608;

    qkv_proj<<<dim3(8, 64, 3), 256, 0, stream>>>(x, wq, wk, wv, Qb, Kb, Vb);
    attn2<<<1024, 256, 0, stream>>>(Qb, Kb, Vb, Cx);
    out_proj<<<dim3(8, 64), 256, 0, stream>>>(Cx, wo, bo, y);
  }
}